// Round 3
// baseline (334.189 us; speedup 1.0000x reference)
//
#include <hip/hip_runtime.h>

#define D 256
#define NCOEF 5
#define KD 1280   // D * NCOEF
#define NB 8192   // batch rows
#define NBLK 512  // persistent grid: 2 blocks/CU * 256 CUs

typedef __bf16 bf16;
typedef bf16 bf16x8 __attribute__((ext_vector_type(8)));
typedef bf16 bf16x4 __attribute__((ext_vector_type(4)));
typedef float f32x4 __attribute__((ext_vector_type(4)));

// async global->LDS, 16B/lane; LDS base wave-uniform, lane i lands at base + i*16
__device__ __forceinline__ void glds16(const bf16* g, bf16* l) {
    __builtin_amdgcn_global_load_lds((const __attribute__((address_space(1))) void*)g,
                                     (__attribute__((address_space(3))) void*)l, 16, 0, 0);
}

// Grid barrier: monotone epoch counter (memset to 0 before each launch).
// All 512 blocks guaranteed co-resident: 64KB LDS -> exactly 2 blocks/CU,
// launch_bounds(256,2) keeps VGPR within the 2-waves/EU budget.
__device__ __forceinline__ void gridbar(unsigned* bar, unsigned target) {
    __syncthreads();   // drain block's memory ops (vmcnt) before release
    if (threadIdx.x == 0) {
        __hip_atomic_fetch_add(bar, 1u, __ATOMIC_RELEASE, __HIP_MEMORY_SCOPE_AGENT);
        int guard = 0;
        while (__hip_atomic_load(bar, __ATOMIC_RELAXED, __HIP_MEMORY_SCOPE_AGENT) < target) {
            __builtin_amdgcn_s_sleep(2);
            if (++guard > (1 << 21)) break;   // safety: fail loud, never hang
        }
    }
    __syncthreads();
    __threadfence();   // acquire: invalidate L1/L2 so we see other XCDs' writes
}

// ---------------------------------------------------------------------------
// pack: coefs[l][i][o][c] fp32 -> Wt[l][o][c*256+i] bf16 via LDS transpose.
// Executed by blocks 0..159 (2 layers * 5 c * 16 tiles).
// ---------------------------------------------------------------------------
__device__ void pack_phase(const float* __restrict__ coefs, float* t, bf16* __restrict__ Wt) {
    int b = blockIdx.x;
    int l = b / 80, rem = b % 80;
    int c = rem / 16, tl = rem % 16;
    int i0 = (tl >> 2) * 64, o0 = (tl & 3) * 64;
    for (int j = threadIdx.x; j < 4096; j += 256) {
        int i = j >> 6, o = j & 63;
        t[i * 65 + o] = coefs[(((size_t)(l * 256 + i0 + i)) * 256 + (o0 + o)) * 5 + c];
    }
    __syncthreads();
    for (int j = threadIdx.x; j < 4096; j += 256) {
        int o = j >> 6, i = j & 63;   // i fastest -> coalesced writes
        Wt[((size_t)(l * 256 + o0 + o)) * KD + c * 256 + i0 + i] = (bf16)t[i * 65 + o];
    }
}

// ---------------------------------------------------------------------------
// LayerNorm + tanh + Jacobi design matrix. Wave handles 4 rows; block 16 rows.
// ---------------------------------------------------------------------------
__device__ void ew_phase(const float* __restrict__ h, const float* __restrict__ scale,
                         const float* __restrict__ bias, const float* __restrict__ alpha_p,
                         bf16* __restrict__ Aout) {
    const int wv = threadIdx.x >> 6;
    const int l  = threadIdx.x & 63;
    const float a = tanhf(alpha_p[0]);

    float rB[3], rC[3];
#pragma unroll
    for (int k = 2; k < NCOEF; k++) {
        float tk  = 2.f * k + 2.f * a;
        float iAk = 1.f / (2.f * k * (k + 2.f * a) * (tk - 2.f));
        rB[k - 2] = (tk - 1.f) * tk * (tk - 2.f) * iAk;
        rC[k - 2] = 2.f * (k + a - 1.f) * (k + a - 1.f) * tk * iAk;
    }
    float4 sc = ((const float4*)scale)[l];
    float4 bi = ((const float4*)bias)[l];
    float scv[4] = {sc.x, sc.y, sc.z, sc.w};
    float biv[4] = {bi.x, bi.y, bi.z, bi.w};

#pragma unroll
    for (int j = 0; j < 4; ++j) {
        int row = blockIdx.x * 16 + wv * 4 + j;
        float4 v = ((const float4*)(h + (size_t)row * D))[l];
        float s  = v.x + v.y + v.z + v.w;
        float ss = v.x * v.x + v.y * v.y + v.z * v.z + v.w * v.w;
#pragma unroll
        for (int off = 32; off > 0; off >>= 1) {
            s  += __shfl_down(s, off);
            ss += __shfl_down(ss, off);
        }
        s  = __shfl(s, 0);
        ss = __shfl(ss, 0);
        float mu   = s * (1.f / D);
        float rstd = rsqrtf(ss * (1.f / D) - mu * mu + 1e-6f);

        float hv[4] = {v.x, v.y, v.z, v.w};
        float P[NCOEF][4];
#pragma unroll
        for (int e = 0; e < 4; e++) {
            float xx = tanhf((hv[e] - mu) * rstd * scv[e] + biv[e]);
            P[0][e] = 1.f;
            P[1][e] = (a + 1.f) * xx;
#pragma unroll
            for (int k = 2; k < NCOEF; k++)
                P[k][e] = rB[k - 2] * xx * P[k - 1][e] - rC[k - 2] * P[k - 2][e];
        }
        bf16* Ar = Aout + (size_t)row * KD + 4 * l;
#pragma unroll
        for (int c = 0; c < NCOEF; c++) {
            bf16x4 o;
#pragma unroll
            for (int e = 0; e < 4; e++) o[e] = (bf16)P[c][e];
            *(bf16x4*)(Ar + c * 256) = o;
        }
    }
}

// ---------------------------------------------------------------------------
// GEMM phase: C[b][o] = (sum_k A[b][k]*W[o][k]) / 256.  Tile 64x64 per block.
// Wave-private split-K (wave w: k in [w*320, w*320+320)), 10 iters of BK=32,
// double-buffered 2x8KB private LDS, glds16 staging, steady-state vmcnt(8)
// (one iteration always in flight; no barriers in the K-loop).
// LDS[row][chunk] = G[row][chunk ^ (row&3)] swizzle for the b128 frag reads.
// ---------------------------------------------------------------------------
__device__ void gemm_phase(const bf16* __restrict__ A, const bf16* __restrict__ W,
                           float* __restrict__ C, bf16* smem) {
    const int tid  = threadIdx.x;
    const int l    = tid & 63;
    const int w    = tid >> 6;
    const int row0 = (blockIdx.x >> 2) * 64;
    const int col0 = (blockIdx.x & 3) * 64;

    bf16* wbase = smem + w * 8192;        // 16 KB per wave
    const int kbase = w * 320;
    const int srow  = l >> 2;             // 0..15
    const int gch   = (l & 3) ^ (srow & 3);
    const bf16* Ag = A + (size_t)(row0 + srow) * KD + kbase + gch * 8;
    const bf16* Bg = W + (size_t)(col0 + srow) * KD + kbase + gch * 8;

    f32x4 acc[4][4] = {};

    auto issue = [&](int it, int b) {
        bf16* sA = wbase + b * 4096;
        bf16* sB = sA + 2048;
        const int ko = it * 32;
#pragma unroll
        for (int t = 0; t < 4; ++t) glds16(Ag + ko + t * 16 * KD, sA + t * 512);
#pragma unroll
        for (int t = 0; t < 4; ++t) glds16(Bg + ko + t * 16 * KD, sB + t * 512);
    };

    issue(0, 0);
    issue(1, 1);

#pragma unroll
    for (int it = 0; it < 10; ++it) {
        if (it == 9) __builtin_amdgcn_s_waitcnt(0x0F70);   // vmcnt(0)
        else         __builtin_amdgcn_s_waitcnt(0x0F78);   // vmcnt(8): cur buf done
        bf16* sA = wbase + (it & 1) * 4096;
        bf16* sB = sA + 2048;
        const int fo = ((l >> 4) ^ (l & 3)) * 8;
        bf16x8 af[4], bf_[4];
#pragma unroll
        for (int t = 0; t < 4; ++t) {
            af[t]  = *(const bf16x8*)(sA + (t * 16 + (l & 15)) * 32 + fo);
            bf_[t] = *(const bf16x8*)(sB + (t * 16 + (l & 15)) * 32 + fo);
        }
#pragma unroll
        for (int tm = 0; tm < 4; tm++)
#pragma unroll
            for (int tn = 0; tn < 4; tn++)
                acc[tm][tn] = __builtin_amdgcn_mfma_f32_16x16x32_bf16(
                    af[tm], bf_[tn], acc[tm][tn], 0, 0, 0);
        if (it < 8) issue(it + 2, it & 1);
    }

    // dump own 64x64 fp32 partial into own region (wave-private, no barrier)
    f32x4* dump = (f32x4*)smem + w * 1024;
#pragma unroll
    for (int tm = 0; tm < 4; tm++)
#pragma unroll
        for (int tn = 0; tn < 4; tn++)
            dump[(tm * 4 + tn) * 64 + l] = acc[tm][tn];
    __syncthreads();

    // wave w reduces the tm=w slice across 4 k-partials; C/D: col=l&15, row=(l>>4)*4+r
    f32x4* base = (f32x4*)smem;
#pragma unroll
    for (int tn = 0; tn < 4; tn++) {
        f32x4 v = base[(w * 4 + tn) * 64 + l];
#pragma unroll
        for (int r = 1; r < 4; r++)
            v += base[r * 1024 + (w * 4 + tn) * 64 + l];
        v *= (1.f / 256.f);
        int gr = row0 + w * 16 + (l >> 4) * 4;
        int gc = col0 + tn * 16 + (l & 15);
#pragma unroll
        for (int j = 0; j < 4; j++)
            C[(size_t)(gr + j) * D + gc] = v[j];
    }
}

// ---------------------------------------------------------------------------
__global__ __launch_bounds__(256, 2) void fused_kernel(
    const float* __restrict__ x, const float* __restrict__ coefs,
    const float* __restrict__ alphas, const float* __restrict__ ln_scale,
    const float* __restrict__ ln_bias, float* __restrict__ out,
    unsigned* __restrict__ bar, bf16* __restrict__ Abuf,
    bf16* __restrict__ Wt, float* __restrict__ h1) {
    __shared__ __align__(16) bf16 smem[32768];   // 64 KB -> 2 blocks/CU

    // phase 0: layer-0 design matrix (all blocks) + weight pack (blocks 0..159)
    ew_phase(x, ln_scale, ln_bias, alphas, Abuf);
    if (blockIdx.x < 160) pack_phase(coefs, (float*)smem, Wt);
    gridbar(bar, NBLK);

    // phase 1: gemm layer 0 -> h1
    gemm_phase(Abuf, Wt, h1, smem);
    gridbar(bar, 2 * NBLK);

    // phase 2: layer-1 design matrix
    ew_phase(h1, ln_scale + D, ln_bias + D, alphas + 1, Abuf);
    gridbar(bar, 3 * NBLK);

    // phase 3: gemm layer 1 -> out
    gemm_phase(Abuf, Wt + (size_t)D * KD, out, smem);
}

// ---------------------------------------------------------------------------
extern "C" void kernel_launch(void* const* d_in, const int* in_sizes, int n_in,
                              void* d_out, int out_size, void* d_ws, size_t ws_size,
                              hipStream_t stream) {
    const float* x        = (const float*)d_in[0];
    const float* coefs    = (const float*)d_in[1];
    const float* alphas   = (const float*)d_in[2];
    const float* ln_scale = (const float*)d_in[3];
    const float* ln_bias  = (const float*)d_in[4];

    char* ws = (char*)d_ws;
    unsigned* bar = (unsigned*)ws;                              // 128 B (zeroed below)
    bf16* Abuf = (bf16*)(ws + 128);                             // 20,971,520 B
    bf16* Wt   = (bf16*)(ws + 128 + 20971520);                  //  1,310,720 B
    float* h1  = (float*)(ws + 128 + 20971520 + 1310720);       //  8,388,608 B

    hipMemsetAsync(d_ws, 0, 128, stream);
    fused_kernel<<<NBLK, 256, 0, stream>>>(x, coefs, alphas, ln_scale, ln_bias,
                                           (float*)d_out, bar, Abuf, Wt, h1);
}

// Round 6
// 123.844 us; speedup vs baseline: 2.6985x; 2.6985x over previous
//
#include <hip/hip_runtime.h>

#define D 256
#define NCOEF 5
#define KD 1280   // D * NCOEF
#define NB 8192   // batch rows
#define NKC 160   // KD / 8 k-chunks per panel

typedef __bf16 bf16;
typedef bf16 bf16x8 __attribute__((ext_vector_type(8)));
typedef bf16 bf16x4 __attribute__((ext_vector_type(4)));
typedef float f32x4 __attribute__((ext_vector_type(4)));

// Tiled operand layout (both A and W): element (r, k) of a 64-row panel p=r/64
// lives at  panel_base + ((k>>3)*64 + (r&63))*8 + (k&7).
// -> any (k-chunk x 64 rows) slice is a contiguous 1KB: perfect glds16 streams,
//    and MFMA fragments read back as clean ds_read_b128 with no swizzle.

// global_load_lds: GLOBAL address is PER-LANE; LDS dest = wave-uniform base,
// lane i lands at base + i*16B.
__device__ __forceinline__ void glds16(const bf16* g, bf16* l) {
    __builtin_amdgcn_global_load_lds((const __attribute__((address_space(1))) void*)g,
                                     (__attribute__((address_space(3))) void*)l, 16, 0, 0);
}

// ---------------------------------------------------------------------------
// ew: LayerNorm + tanh + Jacobi -> tiled design matrix. Block = 16 rows.
// ---------------------------------------------------------------------------
__device__ __forceinline__ void ew_body(const float* __restrict__ h,
                                        const float* __restrict__ scale,
                                        const float* __restrict__ bias,
                                        const float* __restrict__ alpha_p,
                                        bf16* __restrict__ Aout) {
    const int wv = threadIdx.x >> 6;
    const int l  = threadIdx.x & 63;
    const float a = tanhf(alpha_p[0]);

    float rB[3], rC[3];
#pragma unroll
    for (int k = 2; k < NCOEF; k++) {
        float tk  = 2.f * k + 2.f * a;
        float iAk = 1.f / (2.f * k * (k + 2.f * a) * (tk - 2.f));
        rB[k - 2] = (tk - 1.f) * tk * (tk - 2.f) * iAk;
        rC[k - 2] = 2.f * (k + a - 1.f) * (k + a - 1.f) * tk * iAk;
    }
    float4 sc = ((const float4*)scale)[l];
    float4 bi = ((const float4*)bias)[l];
    float scv[4] = {sc.x, sc.y, sc.z, sc.w};
    float biv[4] = {bi.x, bi.y, bi.z, bi.w};

#pragma unroll
    for (int j = 0; j < 4; ++j) {
        int row = blockIdx.x * 16 + wv * 4 + j;
        float4 v = ((const float4*)(h + (size_t)row * D))[l];
        float s  = v.x + v.y + v.z + v.w;
        float ss = v.x * v.x + v.y * v.y + v.z * v.z + v.w * v.w;
#pragma unroll
        for (int off = 32; off > 0; off >>= 1) {
            s  += __shfl_down(s, off);
            ss += __shfl_down(ss, off);
        }
        s  = __shfl(s, 0);
        ss = __shfl(ss, 0);
        float mu   = s * (1.f / D);
        float rstd = rsqrtf(ss * (1.f / D) - mu * mu + 1e-6f);

        float hv[4] = {v.x, v.y, v.z, v.w};
        float P[NCOEF][4];
#pragma unroll
        for (int e = 0; e < 4; e++) {
            float xx = tanhf((hv[e] - mu) * rstd * scv[e] + biv[e]);
            P[0][e] = 1.f;
            P[1][e] = (a + 1.f) * xx;
#pragma unroll
            for (int k = 2; k < NCOEF; k++)
                P[k][e] = rB[k - 2] * xx * P[k - 1][e] - rC[k - 2] * P[k - 2][e];
        }
        // tiled write: k = c*256 + 4*l + e  ->  chunk = c*32 + (l>>1), k&7 = 4*(l&1)+e
        bf16* pan = Aout + (size_t)(row >> 6) * (NKC * 512);
        int r64 = row & 63;
#pragma unroll
        for (int c = 0; c < NCOEF; c++) {
            bf16x4 o;
#pragma unroll
            for (int e = 0; e < 4; e++) o[e] = (bf16)P[c][e];
            *(bf16x4*)(pan + ((size_t)(c * 32 + (l >> 1)) * 64 + r64) * 8 + 4 * (l & 1)) = o;
        }
    }
}

// pack: coefs[l][i][o][c] fp32 -> tiled W (per layer, 64-col panels).
__device__ __forceinline__ void pack_body(const float* __restrict__ coefs, float* t,
                                          bf16* __restrict__ Wt) {
    int b = blockIdx.x;
    int l = b / 80, rem = b % 80;
    int c = rem / 16, tl = rem % 16;
    int i0 = (tl >> 2) * 64, o0 = (tl & 3) * 64;

    for (int j = threadIdx.x; j < 4096; j += 256) {
        int i = j >> 6, o = j & 63;
        t[i * 65 + o] = coefs[(((size_t)(l * 256 + i0 + i)) * 256 + (o0 + o)) * 5 + c];
    }
    __syncthreads();
    // contiguous 8KB write: j = (ih*64 + o)*8 + il ; k = c*256+i0+ih*8+il
    bf16* dst = Wt + (size_t)l * (4 * NKC * 512)
                   + ((size_t)(tl & 3) * NKC + (c * 256 + i0) / 8) * 512;
    for (int j = threadIdx.x; j < 4096; j += 256) {
        int il = j & 7, o = (j >> 3) & 63, ih = j >> 9;
        dst[j] = (bf16)t[(ih * 8 + il) * 65 + o];
    }
}

__global__ __launch_bounds__(256) void prep_kernel(const float* __restrict__ x,
                                                   const float* __restrict__ coefs,
                                                   const float* __restrict__ alphas,
                                                   const float* __restrict__ ln_scale,
                                                   const float* __restrict__ ln_bias,
                                                   bf16* __restrict__ Abuf,
                                                   bf16* __restrict__ Wt) {
    __shared__ float t[64 * 65];
    ew_body(x, ln_scale, ln_bias, alphas, Abuf);
    if (blockIdx.x < 160) pack_body(coefs, t, Wt);
}

__global__ __launch_bounds__(256) void ew_kernel(const float* __restrict__ h,
                                                 const float* __restrict__ scale,
                                                 const float* __restrict__ bias,
                                                 const float* __restrict__ alpha_p,
                                                 bf16* __restrict__ Aout) {
    ew_body(h, scale, bias, alpha_p, Aout);
}

// ---------------------------------------------------------------------------
// GEMM: C[b][o] = (sum_k A[b][k]*W[o][k]) / 256.  64x64 tile per block,
// wave-private split-K (wave w: k-chunks [w*40, w*40+40)), 10 iters BK=32,
// double-buffered private LDS, contiguous glds16, steady-state vmcnt(8).
// RACE FIX (round 5 tripwire): before issuing the prefetch that overwrites
// the buffer read THIS iteration, s_waitcnt lgkmcnt(0) + sched_barrier pin
// the frag ds_reads complete-in-register first. Otherwise a DS-pipe-queued
// ds_read can sample LDS after the async glds write-back lands.
// ---------------------------------------------------------------------------
__global__ __launch_bounds__(256, 2) void gemm_kernel(const bf16* __restrict__ A,
                                                      const bf16* __restrict__ W,
                                                      float* __restrict__ C) {
    __shared__ __align__(16) bf16 smem[32768];   // 64 KB -> 2 blocks/CU

    const int tid  = threadIdx.x;
    const int l    = tid & 63;
    const int w    = tid >> 6;
    const int pm   = blockIdx.x >> 2;    // row panel (0..127)
    const int pn   = blockIdx.x & 3;     // col panel (0..3)

    bf16* wbase = smem + w * 8192;       // 16 KB per wave (2 x (sA 4KB + sB 4KB))
    const bf16* Ap = A + (size_t)pm * (NKC * 512);
    const bf16* Wp = W + (size_t)pn * (NKC * 512);
    const int kc_base = w * 40;          // wave's k-chunk range

    f32x4 acc[4][4] = {};

    auto issue = [&](int it, int b) {
        bf16* sA = wbase + b * 4096;
        bf16* sB = sA + 2048;
        const int kc0 = kc_base + it * 4;
#pragma unroll
        for (int t = 0; t < 4; ++t) glds16(Ap + (kc0 + t) * 512 + l * 8, sA + t * 512);
#pragma unroll
        for (int t = 0; t < 4; ++t) glds16(Wp + (kc0 + t) * 512 + l * 8, sB + t * 512);
    };

    issue(0, 0);
    issue(1, 1);

#pragma unroll
    for (int it = 0; it < 10; ++it) {
        if (it == 9) __builtin_amdgcn_s_waitcnt(0x0F70);   // vmcnt(0)
        else         __builtin_amdgcn_s_waitcnt(0x0F78);   // vmcnt(8): cur set landed
        bf16* sA = wbase + (it & 1) * 4096;
        bf16* sB = sA + 2048;
        bf16x8 af[4], bf_[4];
#pragma unroll
        for (int t = 0; t < 4; ++t) {
            af[t]  = *(const bf16x8*)(sA + (l >> 4) * 512 + (16 * t + (l & 15)) * 8);
            bf_[t] = *(const bf16x8*)(sB + (l >> 4) * 512 + (16 * t + (l & 15)) * 8);
        }
#pragma unroll
        for (int tm = 0; tm < 4; tm++)
#pragma unroll
            for (int tn = 0; tn < 4; tn++)
                acc[tm][tn] = __builtin_amdgcn_mfma_f32_16x16x32_bf16(
                    af[tm], bf_[tn], acc[tm][tn], 0, 0, 0);
        if (it < 8) {
            // WAR-hazard fence: frag reads of buffer (it&1) must be complete
            // in registers before glds overwrites that same buffer.
            __builtin_amdgcn_s_waitcnt(0xC07F);        // lgkmcnt(0) only
            __builtin_amdgcn_sched_barrier(0);
            issue(it + 2, it & 1);
        }
    }

    // dump own 64x64 fp32 partial into own 16KB region (wave-private; same-wave
    // DS ops execute in order, so ds_write after ds_read of this region is safe)
    f32x4* dump = (f32x4*)smem + w * 1024;
#pragma unroll
    for (int tm = 0; tm < 4; tm++)
#pragma unroll
        for (int tn = 0; tn < 4; tn++)
            dump[(tm * 4 + tn) * 64 + l] = acc[tm][tn];
    __syncthreads();

    // wave w reduces tm=w slice across 4 k-partials; C/D: col=l&15, row=(l>>4)*4+r
    f32x4* base = (f32x4*)smem;
#pragma unroll
    for (int tn = 0; tn < 4; tn++) {
        f32x4 v = base[(w * 4 + tn) * 64 + l];
#pragma unroll
        for (int r = 1; r < 4; r++)
            v += base[r * 1024 + (w * 4 + tn) * 64 + l];
        v *= (1.f / 256.f);
        int gr = pm * 64 + w * 16 + (l >> 4) * 4;
        int gc = pn * 64 + tn * 16 + (l & 15);
#pragma unroll
        for (int j = 0; j < 4; j++)
            C[(size_t)(gr + j) * D + gc] = v[j];
    }
}

// ---------------------------------------------------------------------------
extern "C" void kernel_launch(void* const* d_in, const int* in_sizes, int n_in,
                              void* d_out, int out_size, void* d_ws, size_t ws_size,
                              hipStream_t stream) {
    const float* x        = (const float*)d_in[0];
    const float* coefs    = (const float*)d_in[1];
    const float* alphas   = (const float*)d_in[2];
    const float* ln_scale = (const float*)d_in[3];
    const float* ln_bias  = (const float*)d_in[4];
    float* out = (float*)d_out;

    char* ws = (char*)d_ws;
    bf16*  Abuf = (bf16*)ws;                                 // 20,971,520 B
    bf16*  Wt   = (bf16*)(ws + 20971520);                    //  1,310,720 B
    float* h1   = (float*)(ws + 20971520 + 1310720);         //  8,388,608 B

    // layer 0 (prep fuses ew0 + weight pack for both layers)
    prep_kernel<<<512, 256, 0, stream>>>(x, coefs, alphas, ln_scale, ln_bias, Abuf, Wt);
    gemm_kernel<<<512, 256, 0, stream>>>(Abuf, Wt, h1);

    // layer 1
    ew_kernel<<<512, 256, 0, stream>>>(h1, ln_scale + D, ln_bias + D, alphas + 1, Abuf);
    gemm_kernel<<<512, 256, 0, stream>>>(Abuf, Wt + (size_t)4 * NKC * 512, out);
}

// Round 7
// 110.101 us; speedup vs baseline: 3.0353x; 1.1248x over previous
//
#include <hip/hip_runtime.h>

#define D 256
#define NCOEF 5
#define KD 1280         // D * NCOEF
#define NB 8192
#define NKC 160         // k-chunks (of 8) per 64-o panel
#define PANEL (NKC * 512)   // bf16 elems per panel (64 o x 1280 k)

#define SXX_STRIDE 264      // 256 + 8 pad: lane-stride 528B -> 2-way banks (free)
#define SXX_ELEMS (32 * SXX_STRIDE)

typedef __bf16 bf16;
typedef bf16 bf16x8 __attribute__((ext_vector_type(8)));
typedef bf16 bf16x4 __attribute__((ext_vector_type(4)));
typedef float f32x4 __attribute__((ext_vector_type(4)));

// global_load_lds: GLOBAL address is PER-LANE; LDS dest = wave-uniform base,
// lane i lands at base + i*16B.
__device__ __forceinline__ void glds16(const bf16* g, bf16* l) {
    __builtin_amdgcn_global_load_lds((const __attribute__((address_space(1))) void*)g,
                                     (__attribute__((address_space(3))) void*)l, 16, 0, 0);
}

// ---------------------------------------------------------------------------
// pack: coefs[l][i][o][c] fp32 -> tiled W (per layer: 4 panels of 64 o;
// element (o,k) at panel + (k>>3)*512 + (o&63)*8 + (k&7)).  [r6-verified]
// ---------------------------------------------------------------------------
__global__ __launch_bounds__(256) void pack_kernel(const float* __restrict__ coefs,
                                                   bf16* __restrict__ Wt) {
    __shared__ float t[64 * 65];
    int b = blockIdx.x;
    int l = b / 80, rem = b % 80;
    int c = rem / 16, tl = rem % 16;
    int i0 = (tl >> 2) * 64, o0 = (tl & 3) * 64;

    for (int j = threadIdx.x; j < 4096; j += 256) {
        int i = j >> 6, o = j & 63;
        t[i * 65 + o] = coefs[(((size_t)(l * 256 + i0 + i)) * 256 + (o0 + o)) * 5 + c];
    }
    __syncthreads();
    bf16* dst = Wt + (size_t)l * (4 * PANEL)
                   + ((size_t)(tl & 3) * NKC + (c * 256 + i0) / 8) * 512;
    for (int j = threadIdx.x; j < 4096; j += 256) {
        int il = j & 7, o = (j >> 3) & 63, ih = j >> 9;
        dst[j] = (bf16)t[(ih * 8 + il) * 65 + o];
    }
}

// ---------------------------------------------------------------------------
// K-loop half (p = PH template -> Jacobi degree c compile-time per iter).
// 20 iters of BK=32 over k in [PH*640, PH*640+640). W: wave-private dbuf
// glds16 staging, steady-state vmcnt(4), lgkm0+sched_barrier WAR fence.
// A-frags generated from sxx (bf16 tanh values) in registers.
// ---------------------------------------------------------------------------
template <int PH>
__device__ __forceinline__ void gemm_half(f32x4 (&acc)[2][4], const bf16* __restrict__ Wp,
                                          const bf16* sxx, bf16* sW, int l,
                                          float a1, const float* rB, const float* rC) {
#pragma unroll
    for (int it = 0; it < 20; ++it) {
        if (it == 19) __builtin_amdgcn_s_waitcnt(0x0F70);   // vmcnt(0)
        else          __builtin_amdgcn_s_waitcnt(0x0F74);   // vmcnt(4): cur buf landed
        const bf16* sWb = sW + (it & 1) * 2048;

        bf16x8 bfr[4];
#pragma unroll
        for (int tn = 0; tn < 4; ++tn)
            bfr[tn] = *(const bf16x8*)(sWb + (l >> 4) * 512 + (16 * tn + (l & 15)) * 8);

        const int kbase = PH * 640 + it * 32;   // literal after unroll
        const int c = kbase >> 8;               // folds to a constant
        const int i0 = (kbase & 255) + (l >> 4) * 8;

        bf16x8 af[2];
#pragma unroll
        for (int tm = 0; tm < 2; ++tm) {
            if (c == 0) {
#pragma unroll
                for (int j = 0; j < 8; ++j) af[tm][j] = (bf16)1.0f;
            } else {
                bf16x8 xv = *(const bf16x8*)(sxx + (16 * tm + (l & 15)) * SXX_STRIDE + i0);
#pragma unroll
                for (int j = 0; j < 8; ++j) {
                    float x = (float)xv[j];
                    float P;
                    if (c == 1)      P = a1 * x;
                    else if (c == 2) { float P1 = a1 * x; P = rB[0] * x * P1 - rC[0]; }
                    else if (c == 3) { float P1 = a1 * x; float P2 = rB[0] * x * P1 - rC[0];
                                       P = rB[1] * x * P2 - rC[1] * P1; }
                    else             { float P1 = a1 * x; float P2 = rB[0] * x * P1 - rC[0];
                                       float P3 = rB[1] * x * P2 - rC[1] * P1;
                                       P = rB[2] * x * P3 - rC[2] * P2; }
                    af[tm][j] = (bf16)P;
                }
            }
        }

#pragma unroll
        for (int tm = 0; tm < 2; ++tm)
#pragma unroll
            for (int tn = 0; tn < 4; ++tn)
                acc[tm][tn] = __builtin_amdgcn_mfma_f32_16x16x32_bf16(
                    af[tm], bfr[tn], acc[tm][tn], 0, 0, 0);

        if (it < 18) {
            // WAR fence: frag ds_reads of buffer (it&1) complete before glds overwrite
            __builtin_amdgcn_s_waitcnt(0xC07F);        // lgkmcnt(0)
            __builtin_amdgcn_sched_barrier(0);
            bf16* dst = sW + (it & 1) * 2048;
            const int kc0 = PH * 80 + (it + 2) * 4;
#pragma unroll
            for (int t = 0; t < 4; ++t)
                glds16(Wp + (kc0 + t) * 512 + l * 8, dst + t * 512);
        }
    }
}

// ---------------------------------------------------------------------------
// Fused layer: LN + tanh -> sxx (LDS), then GEMM vs tiled W, out = einsum/256.
// Grid 512: block = (32-row slab = blockIdx>>1) x (128-col half = blockIdx&1).
// 4 waves = 2 col-groups x 2 k-halves; split-K reduced via LDS epilogue.
// ---------------------------------------------------------------------------
__global__ __launch_bounds__(256, 2) void layer_kernel(
    const float* __restrict__ h, const float* __restrict__ scale,
    const float* __restrict__ bias, const float* __restrict__ alpha_p,
    const bf16* __restrict__ Wl, float* __restrict__ out) {
    __shared__ __align__(16) bf16 smem[SXX_ELEMS + 4 * 4096];   // 16896 + 32768 B

    const int tid = threadIdx.x;
    const int l   = tid & 63;
    const int w   = tid >> 6;
    const int g   = w >> 1, p = w & 1;      // col-group, k-half
    const int slab = blockIdx.x >> 1;
    const int ch   = blockIdx.x & 1;

    bf16* sxx = smem;
    bf16* sW  = smem + SXX_ELEMS + w * 4096;   // 8 KB/wave: 2 buffers x 4 KB

    const float a  = tanhf(alpha_p[0]);
    const float a1 = a + 1.f;
    float rB[3], rC[3];
#pragma unroll
    for (int k = 2; k < NCOEF; k++) {
        float tk  = 2.f * k + 2.f * a;
        float iAk = 1.f / (2.f * k * (k + 2.f * a) * (tk - 2.f));
        rB[k - 2] = (tk - 1.f) * tk * (tk - 2.f) * iAk;
        rC[k - 2] = 2.f * (k + a - 1.f) * (k + a - 1.f) * tk * iAk;
    }

    float4 sc4 = ((const float4*)scale)[l];
    float4 bi4 = ((const float4*)bias)[l];
    float scv[4] = {sc4.x, sc4.y, sc4.z, sc4.w};
    float biv[4] = {bi4.x, bi4.y, bi4.z, bi4.w};

    // --- LN phase: wave w fills sxx rows 8w..8w+7 ---
    const float* hrows = h + (size_t)slab * 32 * D;
#pragma unroll
    for (int rr = 0; rr < 8; ++rr) {
        int lr = w * 8 + rr;
        float4 v = ((const float4*)(hrows + lr * D))[l];
        float s  = v.x + v.y + v.z + v.w;
        float ss = v.x * v.x + v.y * v.y + v.z * v.z + v.w * v.w;
#pragma unroll
        for (int off = 32; off > 0; off >>= 1) {
            s  += __shfl_down(s, off);
            ss += __shfl_down(ss, off);
        }
        s  = __shfl(s, 0);
        ss = __shfl(ss, 0);
        float mu   = s * (1.f / D);
        float rstd = rsqrtf(ss * (1.f / D) - mu * mu + 1e-6f);
        float hv[4] = {v.x, v.y, v.z, v.w};
        bf16x4 o;
#pragma unroll
        for (int e = 0; e < 4; ++e)
            o[e] = (bf16)tanhf((hv[e] - mu) * rstd * scv[e] + biv[e]);
        *(bf16x4*)(sxx + lr * SXX_STRIDE + 4 * l) = o;
    }

    // --- prologue W prefetch (iters 0,1; runtime p is fine here) ---
    const bf16* Wp = Wl + (size_t)(ch * 2 + g) * PANEL;
#pragma unroll
    for (int it = 0; it < 2; ++it) {
        bf16* dst = sW + it * 2048;
        const int kc0 = p * 80 + it * 4;
#pragma unroll
        for (int t = 0; t < 4; ++t)
            glds16(Wp + (kc0 + t) * 512 + l * 8, dst + t * 512);
    }
    __syncthreads();   // sxx visible to all waves

    f32x4 acc[2][4] = {};
    if (p == 0) gemm_half<0>(acc, Wp, sxx, sW, l, a1, rB, rC);
    else        gemm_half<1>(acc, Wp, sxx, sW, l, a1, rB, rC);

    // --- epilogue: dump partials into own (now idle) staging region, reduce k-halves ---
    f32x4* dump = (f32x4*)(smem + SXX_ELEMS) + w * 512;   // 8 KB = 32x64 fp32
#pragma unroll
    for (int tm = 0; tm < 2; ++tm)
#pragma unroll
        for (int tn = 0; tn < 4; ++tn)
            dump[(tm * 4 + tn) * 64 + l] = acc[tm][tn];
    __syncthreads();

    if (p == 0) {   // waves 0,2: add partner (w+1) partial, scale, store
        f32x4* mine = dump;
        f32x4* part = dump + 512;
#pragma unroll
        for (int tm = 0; tm < 2; ++tm)
#pragma unroll
            for (int tn = 0; tn < 4; ++tn) {
                f32x4 v = mine[(tm * 4 + tn) * 64 + l] + part[(tm * 4 + tn) * 64 + l];
                v *= (1.f / 256.f);
                int gr = slab * 32 + 16 * tm + (l >> 4) * 4;   // C/D: row=(l>>4)*4+r
                int gc = ch * 128 + g * 64 + 16 * tn + (l & 15);
#pragma unroll
                for (int r = 0; r < 4; ++r)
                    out[(size_t)(gr + r) * D + gc] = v[r];
            }
    }
}

// ---------------------------------------------------------------------------
extern "C" void kernel_launch(void* const* d_in, const int* in_sizes, int n_in,
                              void* d_out, int out_size, void* d_ws, size_t ws_size,
                              hipStream_t stream) {
    const float* x        = (const float*)d_in[0];
    const float* coefs    = (const float*)d_in[1];
    const float* alphas   = (const float*)d_in[2];
    const float* ln_scale = (const float*)d_in[3];
    const float* ln_bias  = (const float*)d_in[4];
    float* out = (float*)d_out;

    char* ws = (char*)d_ws;
    bf16*  Wt = (bf16*)ws;                        // 2 layers x 4 panels: 1,310,720 B
    float* h1 = (float*)(ws + 1310720);           // 8,388,608 B

    pack_kernel<<<160, 256, 0, stream>>>(coefs, Wt);
    layer_kernel<<<512, 256, 0, stream>>>(x, ln_scale, ln_bias, alphas, Wt, h1);
    layer_kernel<<<512, 256, 0, stream>>>(h1, ln_scale + D, ln_bias + D, alphas + 1,
                                          Wt + (size_t)4 * PANEL, out);
}

// Round 8
// 103.795 us; speedup vs baseline: 3.2197x; 1.0608x over previous
//
#include <hip/hip_runtime.h>

#define D 256
#define NB 8192
#define KP 1024            // packed K per layer (planes c=1,4,2,3; c=0 folded into beta)
#define NKC 128            // 8-elem k-chunks per 64-o panel
#define PANEL (NKC * 512)  // 65536 bf16 elems per panel (64 o x 1024 k)

#define SXX_STRIDE 264     // 256 + 8 pad -> 2-way bank aliasing (free)
#define SXX_ELEMS (32 * SXX_STRIDE)

typedef __bf16 bf16;
typedef bf16 bf16x8 __attribute__((ext_vector_type(8)));
typedef bf16 bf16x4 __attribute__((ext_vector_type(4)));
typedef float f32x4 __attribute__((ext_vector_type(4)));

// global_load_lds: GLOBAL address is PER-LANE; LDS dest = wave-uniform base,
// lane i lands at base + i*16B.
__device__ __forceinline__ void glds16(const bf16* g, bf16* l) {
    __builtin_amdgcn_global_load_lds((const __attribute__((address_space(1))) void*)g,
                                     (__attribute__((address_space(3))) void*)l, 16, 0, 0);
}

__device__ __forceinline__ float fast_tanh(float x) {
    float e = __expf(2.f * x);          // v_exp_f32 path, ~1e-7 rel
    return 1.f - 2.f / (e + 1.f);
}

// ---------------------------------------------------------------------------
// pack: coefs[l][i][o][c] fp32 -> tiled W planes c in order [1,4,2,3]
// (element (o, k'=plane*256+i) at panel + (k'>>3)*512 + (o&63)*8 + (k'&7));
// blocks 128..135 compute beta[l][o] = sum_i coefs[l][i][o][0] (c=0 folded out).
// ---------------------------------------------------------------------------
__global__ __launch_bounds__(256) void pack_kernel(const float* __restrict__ coefs,
                                                   bf16* __restrict__ Wt,
                                                   float* __restrict__ beta) {
    __shared__ float t[64 * 65];
    __shared__ float accs[4][64];
    int b = blockIdx.x;
    if (b < 128) {
        int l = b >> 6, rem = b & 63;
        int c = (rem >> 4) + 1, tl = rem & 15;
        int plane = (c == 1) ? 0 : (c == 4) ? 1 : (c == 2) ? 2 : 3;
        int i0 = (tl >> 2) * 64, o0 = (tl & 3) * 64;

        for (int j = threadIdx.x; j < 4096; j += 256) {
            int i = j >> 6, o = j & 63;
            t[i * 65 + o] = coefs[(((size_t)(l * 256 + i0 + i)) * 256 + (o0 + o)) * 5 + c];
        }
        __syncthreads();
        bf16* dst = Wt + (size_t)l * (4 * PANEL)
                       + ((size_t)(tl & 3) * NKC + (plane * 256 + i0) / 8) * 512;
        for (int j = threadIdx.x; j < 4096; j += 256) {
            int il = j & 7, o = (j >> 3) & 63, ih = j >> 9;
            dst[j] = (bf16)t[(ih * 8 + il) * 65 + o];
        }
    } else {
        int lidx = b - 128;
        int l = lidx >> 2, o0 = (lidx & 3) * 64;
        int o = threadIdx.x & 63, ig = threadIdx.x >> 6;
        float sum = 0.f;
        for (int m = 0; m < 64; ++m) {
            int i = ig * 64 + m;
            sum += coefs[(((size_t)(l * 256 + i)) * 256 + (o0 + o)) * 5 + 0];
        }
        accs[ig][o] = sum;
        __syncthreads();
        if (threadIdx.x < 64)
            beta[l * 256 + o0 + threadIdx.x] = accs[0][threadIdx.x] + accs[1][threadIdx.x]
                                             + accs[2][threadIdx.x] + accs[3][threadIdx.x];
    }
}

// ---------------------------------------------------------------------------
// K-loop half. Wave p owns planes {p*2, p*2+1} = c in {1,4} / {2,3}.
// 16 iters of BK=32; iteration pair (2j, 2j+1) shares i-chunk j: x loaded once,
// one P1->P4 chain yields BOTH fragments (odd iters: zero VALU).
// W: wave-private dbuf glds16, steady-state vmcnt(4), lgkm0+sched_barrier WAR fence.
// ---------------------------------------------------------------------------
template <int PH>
__device__ __forceinline__ void gemm_half(f32x4 (&acc)[2][4], const bf16* __restrict__ Wp,
                                          const bf16* sxx, bf16* sW, int l, float a1,
                                          float rB0, float rB1, float rB2,
                                          float rC0, float rC1, float rC2) {
    bf16x8 afn[2];   // cached odd-plane fragments
#pragma unroll
    for (int it = 0; it < 16; ++it) {
        if (it == 15) __builtin_amdgcn_s_waitcnt(0x0F70);   // vmcnt(0)
        else          __builtin_amdgcn_s_waitcnt(0x0F74);   // vmcnt(4): cur buf landed
        const bf16* sWb = sW + (it & 1) * 2048;

        bf16x8 bfr[4];
#pragma unroll
        for (int tn = 0; tn < 4; ++tn)
            bfr[tn] = *(const bf16x8*)(sWb + (l >> 4) * 512 + (16 * tn + (l & 15)) * 8);

        bf16x8 af[2];
        if ((it & 1) == 0) {
            const int j  = it >> 1;
            const int i0 = j * 32 + (l >> 4) * 8;
#pragma unroll
            for (int tm = 0; tm < 2; ++tm) {
                bf16x8 xv = *(const bf16x8*)(sxx + (16 * tm + (l & 15)) * SXX_STRIDE + i0);
#pragma unroll
                for (int jj = 0; jj < 8; ++jj) {
                    float x  = (float)xv[jj];
                    float P1 = a1 * x;
                    float P2 = rB0 * x * P1 - rC0;
                    float P3 = rB1 * x * P2 - rC1 * P1;
                    float PA, PB;
                    if (PH == 0) { PA = P1; PB = rB2 * x * P3 - rC2 * P2; }  // c=1, c=4
                    else         { PA = P2; PB = P3; }                        // c=2, c=3
                    af[tm][jj]  = (bf16)PA;
                    afn[tm][jj] = (bf16)PB;
                }
            }
        } else {
            af[0] = afn[0];
            af[1] = afn[1];
        }

#pragma unroll
        for (int tm = 0; tm < 2; ++tm)
#pragma unroll
            for (int tn = 0; tn < 4; ++tn)
                acc[tm][tn] = __builtin_amdgcn_mfma_f32_16x16x32_bf16(
                    af[tm], bfr[tn], acc[tm][tn], 0, 0, 0);

        if (it < 14) {
            // WAR fence: frag ds_reads of buffer (it&1) complete before glds overwrite
            __builtin_amdgcn_s_waitcnt(0xC07F);        // lgkmcnt(0)
            __builtin_amdgcn_sched_barrier(0);
            const int itp   = it + 2;
            const int chunk = (PH * 2 + (itp & 1)) * 8 + (itp >> 1);
            bf16* dst = sW + (it & 1) * 2048;
#pragma unroll
            for (int t = 0; t < 4; ++t)
                glds16(Wp + chunk * 2048 + t * 512 + l * 8, dst + t * 512);
        }
    }
}

// ---------------------------------------------------------------------------
// Fused layer: LN + tanh -> sxx (LDS bf16), then GEMM vs tiled W (K=1024),
// out = (einsum + beta)/256.  Grid 512: (32-row slab) x (128-col half).
// 4 waves = 2 col-groups x 2 plane-pair halves; split-K via LDS epilogue.
// ---------------------------------------------------------------------------
__global__ __launch_bounds__(256, 2) void layer_kernel(
    const float* __restrict__ h, const float* __restrict__ scale,
    const float* __restrict__ bias, const float* __restrict__ alpha_p,
    const bf16* __restrict__ Wl, const float* __restrict__ beta,
    float* __restrict__ out) {
    __shared__ __align__(16) bf16 smem[SXX_ELEMS + 4 * 4096];   // 16896 + 32768 B

    const int tid = threadIdx.x;
    const int l   = tid & 63;
    const int w   = tid >> 6;
    const int g   = w >> 1, p = w & 1;      // col-group, plane-pair half
    const int slab = blockIdx.x >> 1;
    const int ch   = blockIdx.x & 1;

    bf16* sxx = smem;
    bf16* sW  = smem + SXX_ELEMS + w * 4096;   // 8 KB/wave: 2 buffers x 4 KB

    const float a  = tanhf(alpha_p[0]);
    const float a1 = a + 1.f;
    float rB[3], rC[3];
#pragma unroll
    for (int k = 2; k < 5; k++) {
        float tk  = 2.f * k + 2.f * a;
        float iAk = 1.f / (2.f * k * (k + 2.f * a) * (tk - 2.f));
        rB[k - 2] = (tk - 1.f) * tk * (tk - 2.f) * iAk;
        rC[k - 2] = 2.f * (k + a - 1.f) * (k + a - 1.f) * tk * iAk;
    }

    float4 sc4 = ((const float4*)scale)[l];
    float4 bi4 = ((const float4*)bias)[l];
    float scv[4] = {sc4.x, sc4.y, sc4.z, sc4.w};
    float biv[4] = {bi4.x, bi4.y, bi4.z, bi4.w};

    // --- LN phase: wave w fills sxx rows 8w..8w+7 ---
    const float* hrows = h + (size_t)slab * 32 * D;
#pragma unroll
    for (int rr = 0; rr < 8; ++rr) {
        int lr = w * 8 + rr;
        float4 v = ((const float4*)(hrows + lr * D))[l];
        float s  = v.x + v.y + v.z + v.w;
        float ss = v.x * v.x + v.y * v.y + v.z * v.z + v.w * v.w;
#pragma unroll
        for (int off = 32; off > 0; off >>= 1) {
            s  += __shfl_down(s, off);
            ss += __shfl_down(ss, off);
        }
        s  = __shfl(s, 0);
        ss = __shfl(ss, 0);
        float mu   = s * (1.f / D);
        float rstd = rsqrtf(ss * (1.f / D) - mu * mu + 1e-6f);
        float hv[4] = {v.x, v.y, v.z, v.w};
        bf16x4 o;
#pragma unroll
        for (int e = 0; e < 4; ++e)
            o[e] = (bf16)fast_tanh((hv[e] - mu) * rstd * scv[e] + biv[e]);
        *(bf16x4*)(sxx + lr * SXX_STRIDE + 4 * l) = o;
    }

    // --- prologue W prefetch (iters 0,1) ---
    const bf16* Wp = Wl + (size_t)(ch * 2 + g) * PANEL;
#pragma unroll
    for (int itp = 0; itp < 2; ++itp) {
        bf16* dst = sW + itp * 2048;
        const int chunk = (p * 2 + itp) * 8;   // (itp>>1)==0
#pragma unroll
        for (int t = 0; t < 4; ++t)
            glds16(Wp + chunk * 2048 + t * 512 + l * 8, dst + t * 512);
    }
    __syncthreads();   // sxx visible to all waves

    f32x4 acc[2][4] = {};
    if (p == 0) gemm_half<0>(acc, Wp, sxx, sW, l, a1, rB[0], rB[1], rB[2], rC[0], rC[1], rC[2]);
    else        gemm_half<1>(acc, Wp, sxx, sW, l, a1, rB[0], rB[1], rB[2], rC[0], rC[1], rC[2]);

    // --- epilogue: dump partials into (now idle) staging LDS, reduce plane-halves ---
    f32x4* dump = (f32x4*)(smem + SXX_ELEMS) + w * 512;   // 8 KB = 32x64 fp32
#pragma unroll
    for (int tm = 0; tm < 2; ++tm)
#pragma unroll
        for (int tn = 0; tn < 4; ++tn)
            dump[(tm * 4 + tn) * 64 + l] = acc[tm][tn];
    __syncthreads();

    if (p == 0) {   // waves 0,2: add partner (w+1) partial, add beta, scale, store
        f32x4* mine = dump;
        f32x4* part = dump + 512;
#pragma unroll
        for (int tm = 0; tm < 2; ++tm)
#pragma unroll
            for (int tn = 0; tn < 4; ++tn) {
                int gc = ch * 128 + g * 64 + 16 * tn + (l & 15);
                float bv = beta[gc] * (1.f / 256.f);
                f32x4 v = mine[(tm * 4 + tn) * 64 + l] + part[(tm * 4 + tn) * 64 + l];
                int gr = slab * 32 + 16 * tm + (l >> 4) * 4;   // C/D: row=(l>>4)*4+r
#pragma unroll
                for (int r = 0; r < 4; ++r)
                    out[(size_t)(gr + r) * D + gc] = v[r] * (1.f / 256.f) + bv;
            }
    }
}

// ---------------------------------------------------------------------------
extern "C" void kernel_launch(void* const* d_in, const int* in_sizes, int n_in,
                              void* d_out, int out_size, void* d_ws, size_t ws_size,
                              hipStream_t stream) {
    const float* x        = (const float*)d_in[0];
    const float* coefs    = (const float*)d_in[1];
    const float* alphas   = (const float*)d_in[2];
    const float* ln_scale = (const float*)d_in[3];
    const float* ln_bias  = (const float*)d_in[4];
    float* out = (float*)d_out;

    char* ws = (char*)d_ws;
    bf16*  Wt   = (bf16*)ws;                       // 2 layers x 4 panels x 128KB = 1,048,576 B
    float* beta = (float*)(ws + 1048576);          // 2 x 256 x 4 = 2,048 B
    float* h1   = (float*)(ws + 1048576 + 2048);   // 8,388,608 B

    pack_kernel<<<136, 256, 0, stream>>>(coefs, Wt, beta);
    layer_kernel<<<512, 256, 0, stream>>>(x, ln_scale, ln_bias, alphas, Wt, beta, h1);
    layer_kernel<<<512, 256, 0, stream>>>(h1, ln_scale + D, ln_bias + D, alphas + 1,
                                          Wt + (size_t)4 * PANEL, beta + D, out);
}

// Round 9
// 95.821 us; speedup vs baseline: 3.4876x; 1.0832x over previous
//
#include <hip/hip_runtime.h>

#define D 256
#define NB 8192
#define NKC 128            // 8-elem k-chunks per 64-o panel (K=1024 packed)
#define PANEL (NKC * 512)  // 65536 bf16 elems per panel

#define SXX_STRIDE 264     // 256 + 8 pad -> staggered banks
#define SXX_ELEMS (32 * SXX_STRIDE)          // 8448 elems = 16896 B
#define SMEM_BYTES (SXX_ELEMS * 2 + 65536)   // + 8 waves x 8 KB staging = 82432 B

typedef __bf16 bf16;
typedef bf16 bf16x8 __attribute__((ext_vector_type(8)));
typedef bf16 bf16x4 __attribute__((ext_vector_type(4)));
typedef float f32x4 __attribute__((ext_vector_type(4)));

// global_load_lds: GLOBAL address is PER-LANE; LDS dest = wave-uniform base,
// lane i lands at base + i*16B.
__device__ __forceinline__ void glds16(const bf16* g, bf16* l) {
    __builtin_amdgcn_global_load_lds((const __attribute__((address_space(1))) void*)g,
                                     (__attribute__((address_space(3))) void*)l, 16, 0, 0);
}

__device__ __forceinline__ float fast_tanh(float x) {
    float e = __expf(2.f * x);
    return 1.f - 2.f / (e + 1.f);
}

// ---------------------------------------------------------------------------
// pack: coefs[l][i][o][c] fp32 -> tiled W planes c in order [1,4,2,3]
// (element (o, k'=plane*256+i) at panel + (k'>>3)*512 + (o&63)*8 + (k'&7));
// blocks 128..135 compute beta[l][o] = sum_i coefs[l][i][o][0].  [r8-verified]
// ---------------------------------------------------------------------------
__global__ __launch_bounds__(256) void pack_kernel(const float* __restrict__ coefs,
                                                   bf16* __restrict__ Wt,
                                                   float* __restrict__ beta) {
    __shared__ float t[64 * 65];
    __shared__ float accs[4][64];
    int b = blockIdx.x;
    if (b < 128) {
        int l = b >> 6, rem = b & 63;
        int c = (rem >> 4) + 1, tl = rem & 15;
        int plane = (c == 1) ? 0 : (c == 4) ? 1 : (c == 2) ? 2 : 3;
        int i0 = (tl >> 2) * 64, o0 = (tl & 3) * 64;

        for (int j = threadIdx.x; j < 4096; j += 256) {
            int i = j >> 6, o = j & 63;
            t[i * 65 + o] = coefs[(((size_t)(l * 256 + i0 + i)) * 256 + (o0 + o)) * 5 + c];
        }
        __syncthreads();
        bf16* dst = Wt + (size_t)l * (4 * PANEL)
                       + ((size_t)(tl & 3) * NKC + (plane * 256 + i0) / 8) * 512;
        for (int j = threadIdx.x; j < 4096; j += 256) {
            int il = j & 7, o = (j >> 3) & 63, ih = j >> 9;
            dst[j] = (bf16)t[(ih * 8 + il) * 65 + o];
        }
    } else {
        int lidx = b - 128;
        int l = lidx >> 2, o0 = (lidx & 3) * 64;
        int o = threadIdx.x & 63, ig = threadIdx.x >> 6;
        float sum = 0.f;
        for (int m = 0; m < 64; ++m) {
            int i = ig * 64 + m;
            sum += coefs[(((size_t)(l * 256 + i)) * 256 + (o0 + o)) * 5 + 0];
        }
        accs[ig][o] = sum;
        __syncthreads();
        if (threadIdx.x < 64)
            beta[l * 256 + o0 + threadIdx.x] = accs[0][threadIdx.x] + accs[1][threadIdx.x]
                                             + accs[2][threadIdx.x] + accs[3][threadIdx.x];
    }
}

// ---------------------------------------------------------------------------
// K-loop half (r8-verified). Wave p owns planes {p*2, p*2+1} = c {1,4} / {2,3}.
// 16 iters BK=32; pair (2j,2j+1) shares i-chunk: one P1->P4 chain, both frags.
// glds16 dbuf, steady-state vmcnt(4), lgkm0+sched_barrier WAR fence.
// ---------------------------------------------------------------------------
template <int PH>
__device__ __forceinline__ void gemm_half(f32x4 (&acc)[2][4], const bf16* __restrict__ Wp,
                                          const bf16* sxx, bf16* sW, int l, float a1,
                                          float rB0, float rB1, float rB2,
                                          float rC0, float rC1, float rC2) {
    bf16x8 afn[2];
#pragma unroll
    for (int it = 0; it < 16; ++it) {
        if (it == 15) __builtin_amdgcn_s_waitcnt(0x0F70);   // vmcnt(0)
        else          __builtin_amdgcn_s_waitcnt(0x0F74);   // vmcnt(4)
        const bf16* sWb = sW + (it & 1) * 2048;

        bf16x8 bfr[4];
#pragma unroll
        for (int tn = 0; tn < 4; ++tn)
            bfr[tn] = *(const bf16x8*)(sWb + (l >> 4) * 512 + (16 * tn + (l & 15)) * 8);

        bf16x8 af[2];
        if ((it & 1) == 0) {
            const int j  = it >> 1;
            const int i0 = j * 32 + (l >> 4) * 8;
#pragma unroll
            for (int tm = 0; tm < 2; ++tm) {
                bf16x8 xv = *(const bf16x8*)(sxx + (16 * tm + (l & 15)) * SXX_STRIDE + i0);
#pragma unroll
                for (int jj = 0; jj < 8; ++jj) {
                    float x  = (float)xv[jj];
                    float P1 = a1 * x;
                    float P2 = rB0 * x * P1 - rC0;
                    float P3 = rB1 * x * P2 - rC1 * P1;
                    float PA, PB;
                    if (PH == 0) { PA = P1; PB = rB2 * x * P3 - rC2 * P2; }  // c=1,4
                    else         { PA = P2; PB = P3; }                        // c=2,3
                    af[tm][jj]  = (bf16)PA;
                    afn[tm][jj] = (bf16)PB;
                }
            }
        } else {
            af[0] = afn[0];
            af[1] = afn[1];
        }

#pragma unroll
        for (int tm = 0; tm < 2; ++tm)
#pragma unroll
            for (int tn = 0; tn < 4; ++tn)
                acc[tm][tn] = __builtin_amdgcn_mfma_f32_16x16x32_bf16(
                    af[tm], bfr[tn], acc[tm][tn], 0, 0, 0);

        if (it < 14) {
            __builtin_amdgcn_s_waitcnt(0xC07F);        // lgkmcnt(0): WAR fence
            __builtin_amdgcn_sched_barrier(0);
            const int itp   = it + 2;
            const int chunk = (PH * 2 + (itp & 1)) * 8 + (itp >> 1);
            bf16* dst = sW + (it & 1) * 2048;
#pragma unroll
            for (int t = 0; t < 4; ++t)
                glds16(Wp + chunk * 2048 + t * 512 + l * 8, dst + t * 512);
        }
    }
}

// ---------------------------------------------------------------------------
// Fused 2-layer kernel. Block = one 32-row slab x all 256 cols, 8 waves =
// 4 col-panels (g) x 2 plane-pair K-halves (p). Layer 0's h1 never leaves the
// block: split-K reduce -> h1 panels in LDS (fp32, +beta0, /256) -> in-block
// LN -> layer 1 -> global out. Staging regions (8 KB/wave) timeshare as:
// K-loop dbuf -> p=1 dump (own) -> h1 panels (even-wave regions) -> K1 dbuf.
// ---------------------------------------------------------------------------
__global__ __launch_bounds__(512, 2) void fused2_kernel(
    const float* __restrict__ x, const float* __restrict__ ln_scale,
    const float* __restrict__ ln_bias, const float* __restrict__ alphas,
    const bf16* __restrict__ Wt, const float* __restrict__ beta,
    float* __restrict__ out) {
    extern __shared__ __align__(16) bf16 smem[];
    bf16* sxx  = smem;                 // 16896 B
    bf16* stag = smem + SXX_ELEMS;     // 65536 B: wave w owns elems [w*4096, +4096)

    const int tid = threadIdx.x;
    const int l   = tid & 63;
    const int w   = tid >> 6;
    const int g   = w >> 1, p = w & 1;
    const int slab = blockIdx.x;

    bf16* sW = stag + w * 4096;        // 8 KB dbuf (2 x 4 KB)

#pragma unroll
    for (int L = 0; L < 2; ++L) {
        const float* scale = ln_scale + L * D;
        const float* biasp = ln_bias + L * D;
        const bf16*  Wl    = Wt + (size_t)L * 4 * PANEL;
        const float* bet   = beta + L * D;

        const float a  = tanhf(alphas[L]);
        const float a1 = a + 1.f;
        float rB[3], rC[3];
#pragma unroll
        for (int k = 2; k < 5; k++) {
            float tk  = 2.f * k + 2.f * a;
            float iAk = 1.f / (2.f * k * (k + 2.f * a) * (tk - 2.f));
            rB[k - 2] = (tk - 1.f) * tk * (tk - 2.f) * iAk;
            rC[k - 2] = 2.f * (k + a - 1.f) * (k + a - 1.f) * tk * iAk;
        }

        float4 sc4 = ((const float4*)scale)[l];
        float4 bi4 = ((const float4*)biasp)[l];
        float scv[4] = {sc4.x, sc4.y, sc4.z, sc4.w};
        float biv[4] = {bi4.x, bi4.y, bi4.z, bi4.w};

        // --- LN: 4 rows per wave ---
#pragma unroll
        for (int rr = 0; rr < 4; ++rr) {
            int lr = w * 4 + rr;
            float4 v;
            if (L == 0) {
                v = ((const float4*)(x + ((size_t)slab * 32 + lr) * D))[l];
            } else {
                // h1 panel (l>>4) lives in even-wave region 2*(l>>4): elems (l>>4)*8192
                const float* hp = (const float*)(stag + (size_t)(l >> 4) * 8192);
                v = *(const float4*)(hp + lr * 64 + (l & 15) * 4);
            }
            float s  = v.x + v.y + v.z + v.w;
            float ss = v.x * v.x + v.y * v.y + v.z * v.z + v.w * v.w;
#pragma unroll
            for (int off = 32; off > 0; off >>= 1) {
                s  += __shfl_down(s, off);
                ss += __shfl_down(ss, off);
            }
            s  = __shfl(s, 0);
            ss = __shfl(ss, 0);
            float mu   = s * (1.f / D);
            float rstd = rsqrtf(ss * (1.f / D) - mu * mu + 1e-6f);
            float hv[4] = {v.x, v.y, v.z, v.w};
            bf16x4 o;
#pragma unroll
            for (int e = 0; e < 4; ++e)
                o[e] = (bf16)fast_tanh((hv[e] - mu) * rstd * scv[e] + biv[e]);
            *(bf16x4*)(sxx + lr * SXX_STRIDE + 4 * l) = o;
        }
        __syncthreads();   // sxx ready; h1 (L=1) fully consumed -> staging free

        // --- prologue W prefetch ---
        const bf16* Wp = Wl + (size_t)g * PANEL;
#pragma unroll
        for (int itp = 0; itp < 2; ++itp) {
            bf16* dst = sW + itp * 2048;
            const int chunk = (p * 2 + itp) * 8;
#pragma unroll
            for (int t = 0; t < 4; ++t)
                glds16(Wp + chunk * 2048 + t * 512 + l * 8, dst + t * 512);
        }

        f32x4 acc[2][4] = {};
        if (p == 0) gemm_half<0>(acc, Wp, sxx, sW, l, a1, rB[0], rB[1], rB[2], rC[0], rC[1], rC[2]);
        else        gemm_half<1>(acc, Wp, sxx, sW, l, a1, rB[0], rB[1], rB[2], rC[0], rC[1], rC[2]);

        // --- split-K reduce: p=1 dumps into OWN (idle) region ---
        if (p == 1) {
            f32x4* dumpr = (f32x4*)(stag + (size_t)w * 4096);
#pragma unroll
            for (int tm = 0; tm < 2; ++tm)
#pragma unroll
                for (int tn = 0; tn < 4; ++tn)
                    dumpr[(tm * 4 + tn) * 64 + l] = acc[tm][tn];
        }
        __syncthreads();

        if (p == 0) {
            f32x4* part = (f32x4*)(stag + (size_t)(w + 1) * 4096);
            if (L == 0) {
                // write h1 panel g (fp32, 32x64) into OWN region
                float* hp = (float*)(stag + (size_t)w * 4096);
#pragma unroll
                for (int tm = 0; tm < 2; ++tm)
#pragma unroll
                    for (int tn = 0; tn < 4; ++tn) {
                        int lc = 16 * tn + (l & 15);
                        float bv = bet[g * 64 + lc] * (1.f / 256.f);
                        f32x4 v = acc[tm][tn] + part[(tm * 4 + tn) * 64 + l];
                        int lr0 = 16 * tm + (l >> 4) * 4;
#pragma unroll
                        for (int r = 0; r < 4; ++r)
                            hp[(lr0 + r) * 64 + lc] = v[r] * (1.f / 256.f) + bv;
                    }
            } else {
#pragma unroll
                for (int tm = 0; tm < 2; ++tm)
#pragma unroll
                    for (int tn = 0; tn < 4; ++tn) {
                        int gc = g * 64 + 16 * tn + (l & 15);
                        float bv = bet[gc] * (1.f / 256.f);
                        f32x4 v = acc[tm][tn] + part[(tm * 4 + tn) * 64 + l];
                        int gr = slab * 32 + 16 * tm + (l >> 4) * 4;
#pragma unroll
                        for (int r = 0; r < 4; ++r)
                            out[(size_t)(gr + r) * D + gc] = v[r] * (1.f / 256.f) + bv;
                    }
            }
        }
        __syncthreads();   // h1 visible before next layer's LN
    }
}

// ---------------------------------------------------------------------------
extern "C" void kernel_launch(void* const* d_in, const int* in_sizes, int n_in,
                              void* d_out, int out_size, void* d_ws, size_t ws_size,
                              hipStream_t stream) {
    const float* x        = (const float*)d_in[0];
    const float* coefs    = (const float*)d_in[1];
    const float* alphas   = (const float*)d_in[2];
    const float* ln_scale = (const float*)d_in[3];
    const float* ln_bias  = (const float*)d_in[4];
    float* out = (float*)d_out;

    char* ws = (char*)d_ws;
    bf16*  Wt   = (bf16*)ws;               // 1,048,576 B
    float* beta = (float*)(ws + 1048576);  // 2,048 B

    hipFuncSetAttribute((const void*)fused2_kernel,
                        hipFuncAttributeMaxDynamicSharedMemorySize, SMEM_BYTES);

    pack_kernel<<<136, 256, 0, stream>>>(coefs, Wt, beta);
    fused2_kernel<<<256, 512, SMEM_BYTES, stream>>>(x, ln_scale, ln_bias, alphas,
                                                    Wt, beta, out);
}